// Round 4
// baseline (1014.044 us; speedup 1.0000x reference)
//
#include <hip/hip_runtime.h>
#include <hip/hip_bf16.h>
#include <math.h>

#define BATCH 4
#define NHEADS 16
#define SEQ 2048
#define HDIM 128
#define NPAT 4

#define BM 128
#define BN 64
#define NTHREADS 256

typedef _Float16 f16x8 __attribute__((ext_vector_type(8)));
typedef _Float16 f16x4 __attribute__((ext_vector_type(4)));
typedef float floatx4 __attribute__((ext_vector_type(4)));

// ---------------- selector: per-head pattern argmax ----------------
__global__ void sel_kernel(const float* __restrict__ w1, const float* __restrict__ b1,
                           const float* __restrict__ w2, const float* __restrict__ b2,
                           int* __restrict__ pat_idx) {
  int h = threadIdx.x;
  if (h >= NHEADS) return;
  float f0 = 1.0f;               // S / MAX_SEQ_LEN = 2048/2048
  float f1 = (float)h / 12.0f;
  float f2 = 0.5f;
  float acc[NPAT] = {b2[0], b2[1], b2[2], b2[3]};
  for (int j = 0; j < 32; ++j) {
    float hj = f0 * w1[j] + f1 * w1[32 + j] + f2 * w1[64 + j] + b1[j];
    hj = fmaxf(hj, 0.0f);
    for (int p = 0; p < NPAT; ++p) acc[p] += hj * w2[j * NPAT + p];
  }
  int best = 0;
  float bv = acc[0];
  for (int p = 1; p < NPAT; ++p) {
    if (acc[p] > bv) { bv = acc[p]; best = p; }   // strict > : first-max like jnp.argmax
  }
  pat_idx[h] = best;
}

// ---------------- binarize pattern masks to bit words ----------------
// Reference does sigmoid(x) > 0.5 IN FP32. For 0 < x <~ 1.5*2^-24, fp32
// sigmoid rounds to exactly 0.5 -> mask 0, unlike the mathematical x>0.
// Replicate: correctly-rounded fp32 exp (via double), fp32 add, IEEE fp32 div.
__device__ __forceinline__ bool sig_gt_half(float x) {
  float t = (float)exp(-(double)x);   // correctly-rounded fp32 exp(-x)
  float s = 1.0f / (1.0f + t);        // fp32 IEEE add + div (default HIP: correct)
  return s > 0.5f;
}

__global__ void bin_kernel(const float* __restrict__ pm, unsigned int* __restrict__ bits) {
  int t = blockIdx.x * blockDim.x + threadIdx.x;  // one 32-col word per thread
  const float4* s4 = (const float4*)(pm + (size_t)t * 32);
  unsigned int w = 0;
#pragma unroll
  for (int i = 0; i < 8; ++i) {
    float4 v = s4[i];
    w |= (sig_gt_half(v.x) ? 1u : 0u) << (i * 4 + 0);
    w |= (sig_gt_half(v.y) ? 1u : 0u) << (i * 4 + 1);
    w |= (sig_gt_half(v.z) ? 1u : 0u) << (i * 4 + 2);
    w |= (sig_gt_half(v.w) ? 1u : 0u) << (i * 4 + 3);
  }
  bits[t] = w;
}

// ---------------- flash attention with multiplicative binary mask ----------------
// Grid: BATCH*NHEADS*(SEQ/BM) blocks, 256 threads (4 waves), wave owns 32 q-rows.
// Numerics: fp16 operands (10 mantissa bits), fp32 MFMA accumulate. P clamped out
// of fp16 subnormal range and quantized BEFORE summing l so numerator/denominator
// use identical weights.
__global__ __launch_bounds__(NTHREADS, 2) void flash_kernel(
    const float* __restrict__ Q, const float* __restrict__ K, const float* __restrict__ V,
    const unsigned int* __restrict__ bits, const int* __restrict__ pat_idx,
    float* __restrict__ out) {
  __shared__ alignas(16) _Float16 k_lds[BN][HDIM + 8];   // K tile [kcol][d]          17408 B
  __shared__ alignas(16) _Float16 vt_lds[HDIM][BN + 8];  // V^T [d][kcol]             18432 B
  __shared__ alignas(16) _Float16 p_lds[4][32][BN + 8];  // per-wave P C->A transform 18432 B
  __shared__ unsigned int maskw[BM][2];                  //                            1024 B

  const int tid = threadIdx.x;
  const int wave = tid >> 6;
  const int lane = tid & 63;
  const int l16 = lane & 15;
  const int quad = lane >> 4;

  const int bh = blockIdx.x >> 4;       // 0..63 = b*16+h
  const int qt = blockIdx.x & 15;
  const int h = bh & (NHEADS - 1);
  const int qbase = qt * BM;
  const int pat = pat_idx[h];

  // (1/sqrt(128)) * log2(e): softmax in base 2; masked entries -> score exactly 0
  const float SCL = 0.08838834764831845f * 1.4426950408889634f;
  const float P_MIN = 6.103515625e-05f;  // 2^-14: fp16 normal floor; below -> 0

  // Q fragments, A-layout: A[m=lane&15][k=quad*8+j], registers for whole kernel
  f16x8 qf[2][4];
#pragma unroll
  for (int mt = 0; mt < 2; ++mt) {
    const int row = qbase + wave * 32 + mt * 16 + l16;
    const float* qp = Q + ((size_t)bh * SEQ + row) * HDIM;
#pragma unroll
    for (int ks = 0; ks < 4; ++ks) {
      const float4* p4 = (const float4*)(qp + ks * 32 + quad * 8);
      float4 a = p4[0], c = p4[1];
      f16x8 f;
      f[0] = (_Float16)a.x; f[1] = (_Float16)a.y; f[2] = (_Float16)a.z; f[3] = (_Float16)a.w;
      f[4] = (_Float16)c.x; f[5] = (_Float16)c.y; f[6] = (_Float16)c.z; f[7] = (_Float16)c.w;
      qf[mt][ks] = f;
    }
  }

  floatx4 o_acc[2][8];
#pragma unroll
  for (int mt = 0; mt < 2; ++mt)
#pragma unroll
    for (int n = 0; n < 8; ++n) o_acc[mt][n] = (floatx4){0.f, 0.f, 0.f, 0.f};
  float m_run[2][4], l_run[2][4];
#pragma unroll
  for (int mt = 0; mt < 2; ++mt)
#pragma unroll
    for (int r = 0; r < 4; ++r) { m_run[mt][r] = -INFINITY; l_run[mt][r] = 0.0f; }

  const float* kg_bh = K + (size_t)bh * SEQ * HDIM;
  const float* vg_bh = V + (size_t)bh * SEQ * HDIM;
  const unsigned int* bits_p = bits + ((size_t)pat * SEQ + qbase) * (SEQ / 32);

  for (int kt = 0; kt < SEQ / BN; ++kt) {
    __syncthreads();  // previous iter's LDS reads done before restage
    {
      const float* kg = kg_bh + (size_t)kt * BN * HDIM;
      const float* vg = vg_bh + (size_t)kt * BN * HDIM;
#pragma unroll
      for (int i = 0; i < 8; ++i) {
        int idx = tid + NTHREADS * i;  // 0..2047 float4-chunks
        int r = idx >> 5;              // kcol 0..63
        int c4 = idx & 31;             // float4 within row
        float4 kv = ((const float4*)(kg + r * HDIM))[c4];
        f16x4 kb;
        kb[0] = (_Float16)kv.x; kb[1] = (_Float16)kv.y;
        kb[2] = (_Float16)kv.z; kb[3] = (_Float16)kv.w;
        *(f16x4*)&k_lds[r][c4 * 4] = kb;
        float4 vv = ((const float4*)(vg + r * HDIM))[c4];
        vt_lds[c4 * 4 + 0][r] = (_Float16)vv.x;
        vt_lds[c4 * 4 + 1][r] = (_Float16)vv.y;
        vt_lds[c4 * 4 + 2][r] = (_Float16)vv.z;
        vt_lds[c4 * 4 + 3][r] = (_Float16)vv.w;
      }
      int mr = tid >> 1, mw = tid & 1;
      maskw[mr][mw] = bits_p[(size_t)mr * (SEQ / 32) + kt * 2 + mw];
    }
    __syncthreads();

    // ---- S = Q @ K^T ----
    floatx4 sf[2][4];
#pragma unroll
    for (int mt = 0; mt < 2; ++mt)
#pragma unroll
      for (int nt = 0; nt < 4; ++nt) sf[mt][nt] = (floatx4){0.f, 0.f, 0.f, 0.f};
#pragma unroll
    for (int nt = 0; nt < 4; ++nt) {
#pragma unroll
      for (int ks = 0; ks < 4; ++ks) {
        f16x8 bf = *(const f16x8*)&k_lds[nt * 16 + l16][ks * 32 + quad * 8];
#pragma unroll
        for (int mt = 0; mt < 2; ++mt)
          sf[mt][nt] = __builtin_amdgcn_mfma_f32_16x16x32_f16(qf[mt][ks], bf, sf[mt][nt], 0, 0, 0);
      }
    }

    // ---- mask (multiplicative!) + online softmax (base 2) ----
    float alpha[2][4];
#pragma unroll
    for (int mt = 0; mt < 2; ++mt) {
#pragma unroll
      for (int r = 0; r < 4; ++r) {
        int rl = wave * 32 + mt * 16 + quad * 4 + r;   // C-layout row
        unsigned int w0 = maskw[rl][0], w1 = maskw[rl][1];
#pragma unroll
        for (int nt = 0; nt < 4; ++nt) {
          unsigned int wd = (nt & 2) ? w1 : w0;
          int bit = ((nt & 1) << 4) | l16;             // C-layout col = nt*16 + l16
          float s = sf[mt][nt][r];
          sf[mt][nt][r] = ((wd >> bit) & 1u) ? s * SCL : 0.0f;  // masked -> score exactly 0
        }
        float mx = fmaxf(fmaxf(sf[mt][0][r], sf[mt][1][r]), fmaxf(sf[mt][2][r], sf[mt][3][r]));
        mx = fmaxf(mx, __shfl_xor(mx, 1));
        mx = fmaxf(mx, __shfl_xor(mx, 2));
        mx = fmaxf(mx, __shfl_xor(mx, 4));
        mx = fmaxf(mx, __shfl_xor(mx, 8));
        float m_old = m_run[mt][r];
        float m_new = fmaxf(m_old, mx);
        float a = exp2f(m_old - m_new);                // first iter: exp2(-inf)=0
        alpha[mt][r] = a;
        m_run[mt][r] = m_new;
        float ps = 0.0f;
#pragma unroll
        for (int nt = 0; nt < 4; ++nt) {
          float p = exp2f(sf[mt][nt][r] - m_new);      // masked entries contribute 2^(0-m)
          if (p < P_MIN) p = 0.0f;                     // stay out of fp16 subnormals
          float pqf = (float)(_Float16)p;              // quantize FIRST...
          sf[mt][nt][r] = pqf;
          ps += pqf;                                   // ...then sum: l matches MFMA weights
        }
        ps += __shfl_xor(ps, 1);
        ps += __shfl_xor(ps, 2);
        ps += __shfl_xor(ps, 4);
        ps += __shfl_xor(ps, 8);
        l_run[mt][r] = l_run[mt][r] * a + ps;
      }
    }

    // ---- rescale O ----
#pragma unroll
    for (int mt = 0; mt < 2; ++mt)
#pragma unroll
      for (int n = 0; n < 8; ++n)
#pragma unroll
        for (int r = 0; r < 4; ++r) o_acc[mt][n][r] *= alpha[mt][r];

    // ---- P: C-layout -> A-layout via per-wave LDS (m120-verified transform) ----
#pragma unroll
    for (int mt = 0; mt < 2; ++mt)
#pragma unroll
      for (int nt = 0; nt < 4; ++nt)
#pragma unroll
        for (int r = 0; r < 4; ++r)
          p_lds[wave][mt * 16 + quad * 4 + r][nt * 16 + l16] = (_Float16)sf[mt][nt][r];
    // per-wave region: compiler inserts lgkmcnt waits

    // ---- O += P @ V ----
#pragma unroll
    for (int ks = 0; ks < 2; ++ks) {
      f16x8 pa[2];
#pragma unroll
      for (int mt = 0; mt < 2; ++mt)
        pa[mt] = *(const f16x8*)&p_lds[wave][mt * 16 + l16][ks * 32 + quad * 8];
#pragma unroll
      for (int nt = 0; nt < 8; ++nt) {
        f16x8 vb = *(const f16x8*)&vt_lds[nt * 16 + l16][ks * 32 + quad * 8];
#pragma unroll
        for (int mt = 0; mt < 2; ++mt)
          o_acc[mt][nt] = __builtin_amdgcn_mfma_f32_16x16x32_f16(pa[mt], vb, o_acc[mt][nt], 0, 0, 0);
      }
    }
  }

  // ---- epilogue: O / l ----
#pragma unroll
  for (int mt = 0; mt < 2; ++mt) {
#pragma unroll
    for (int r = 0; r < 4; ++r) {
      const float inv = 1.0f / l_run[mt][r];
      const int row = qbase + wave * 32 + mt * 16 + quad * 4 + r;
      float* og = out + ((size_t)bh * SEQ + row) * HDIM + l16;
#pragma unroll
      for (int n = 0; n < 8; ++n) og[n * 16] = o_acc[mt][n][r] * inv;
    }
  }
}

extern "C" void kernel_launch(void* const* d_in, const int* in_sizes, int n_in,
                              void* d_out, int out_size, void* d_ws, size_t ws_size,
                              hipStream_t stream) {
  const float* Q  = (const float*)d_in[0];
  const float* K  = (const float*)d_in[1];
  const float* V  = (const float*)d_in[2];
  const float* pm = (const float*)d_in[3];
  const float* w1 = (const float*)d_in[4];
  const float* b1 = (const float*)d_in[5];
  const float* w2 = (const float*)d_in[6];
  const float* b2 = (const float*)d_in[7];
  float* out = (float*)d_out;

  int* pat_idx = (int*)d_ws;
  unsigned int* bits = (unsigned int*)((char*)d_ws + 256);  // 4*2048*64 words = 2 MB

  sel_kernel<<<1, 64, 0, stream>>>(w1, b1, w2, b2, pat_idx);
  bin_kernel<<<(NPAT * SEQ * (SEQ / 32)) / 256, 256, 0, stream>>>(pm, bits);
  flash_kernel<<<BATCH * NHEADS * (SEQ / BM), NTHREADS, 0, stream>>>(Q, K, V, bits, pat_idx, out);
}